// Round 6
// baseline (812.095 us; speedup 1.0000x reference)
//
#include <hip/hip_runtime.h>

#define D 128
#define NNODES 100000
#define NEDGES 1600000
#define BN_EPS 1e-5f
#define NB_STATS 2048
#define NBLK_P 391   // ceil(NNODES/256)

// Scratch layout, offsets in float slots RELATIVE to scratch base `sb`.
// sb = d_ws when ws_size is large enough, else the E_X region of d_out
// (then copy is tail-only and overwrites scratch last).
#define OFF_AX     0          // 12.8M f32
#define OFF_BX16   12800000   // 12.8M bf16 = 6.4M slots
#define OFF_ESRC   19200000   // 1.6M int
#define OFF_ORDER  20800000   // 1.6M int
#define OFF_INDEG  22400000   // 100k int
#define OFF_LEXC   22620000   // 100k int
#define OFF_BPART  22730000   // 512 int
#define OFF_BSCAN  22731000   // 512 int
#define OFF_PSUM   22740000   // 2048*128 f32
#define OFF_PSQ    23010000   // 2048*128 f32
#define OFF_SCALE  23280000   // 128
#define OFF_SHIFT  23280128   // 128
#define WS_NEED_BYTES 93200000ull

#define MAIN_GEMM 512
#define MAIN_EDGE 2048
#define MAIN_AGG  2048
#define MAIN_FIN  2048

// E_X copy plan in float4 units (total NEDGES*D/4 = 51,200,000).
// Dedicated copy blocks FIRST in dispatch order, co-resident with compute.
#define NCOPY_SM   256
#define CPB_SM     16000L
#define NCOPY_AGG  512
#define CPB_AGG    39000L
#define HIST_C0    0L
#define FILL_C0    4096000L          // 256*16000
#define AGG_C0     8192000L
#define FIN_C0     28160000L         // 8192000 + 512*39000
#define TAIL_C0    32256000L
#define C_TOTAL    51200000L

static __device__ __forceinline__ unsigned short f2bf(float f) {
    unsigned int u = __float_as_uint(f);
    u = (u + 0x7FFF + ((u >> 16) & 1)) >> 16;   // RNE, finite data
    return (unsigned short)u;
}
static __device__ __forceinline__ float bf_lo(unsigned v) {
    return __uint_as_float(v << 16);
}
static __device__ __forceinline__ float bf_hi(unsigned v) {
    return __uint_as_float(v & 0xFFFF0000u);
}

// Contiguous per-block copy stripe (coalesced 16B/lane).
static __device__ __forceinline__ void copy_blk(
    const float4* __restrict__ s, float4* __restrict__ d,
    long base, long cnt)
{
    const long end = base + cnt;
    for (long i = base + threadIdx.x; i < end; i += 256)
        d[i] = s[i];
}

// ---------------------------------------------------------------------------
// GEMM: Y[i,d] = sum_k X[i,k] * W[d,k] + bias[d]
// Even blocks -> A (f32 AX), odd blocks -> B (bf16 BX16). No copy duty
// (66KB LDS: copy blocks would steal residency slots).
// ---------------------------------------------------------------------------
__global__ __launch_bounds__(256, 2) void gemm2_kernel(
    const float* __restrict__ X,
    const float* __restrict__ Aw, const float* __restrict__ Ab,
    const float* __restrict__ Bw, const float* __restrict__ Bb,
    float* __restrict__ AX, unsigned short* __restrict__ BX16)
{
    const bool isB = (blockIdx.x & 1);
    const float* __restrict__ W    = isB ? Bw : Aw;
    const float* __restrict__ bias = isB ? Bb : Ab;

    __shared__ float Ws[D * 132];
    const float4* W4 = (const float4*)W;
    for (int i = threadIdx.x; i < D * D / 4; i += 256) {
        int d  = i >> 5;
        int k4 = i & 31;
        float4 w = W4[i];
        *(float4*)&Ws[d * 132 + 4 * k4] = w;
    }
    __syncthreads();

    const int rg = threadIdx.x >> 5;   // 0..7  -> 4 rows each
    const int cg = threadIdx.x & 31;   // 0..31 -> cols cg+32j

    float b[4];
#pragma unroll
    for (int j = 0; j < 4; ++j) b[j] = bias[cg + 32 * j];

    const int ntiles = NNODES / 32;    // 3125 exact
    for (int t = (blockIdx.x >> 1); t < ntiles; t += (MAIN_GEMM >> 1)) {
        const int row0 = t * 32 + rg * 4;
        float acc[4][4];
#pragma unroll
        for (int r = 0; r < 4; ++r)
#pragma unroll
            for (int j = 0; j < 4; ++j) acc[r][j] = b[j];

        const float* xbase = X + (size_t)row0 * D;
#pragma unroll 4
        for (int k = 0; k < D; k += 4) {
            float4 xr[4];
#pragma unroll
            for (int r = 0; r < 4; ++r)
                xr[r] = *(const float4*)&xbase[r * D + k];
            float4 wv[4];
#pragma unroll
            for (int j = 0; j < 4; ++j)
                wv[j] = *(const float4*)&Ws[(cg + 32 * j) * 132 + k];
#pragma unroll
            for (int r = 0; r < 4; ++r)
#pragma unroll
                for (int j = 0; j < 4; ++j)
                    acc[r][j] += xr[r].x * wv[j].x + xr[r].y * wv[j].y +
                                 xr[r].z * wv[j].z + xr[r].w * wv[j].w;
        }
        if (isB) {
#pragma unroll
            for (int r = 0; r < 4; ++r) {
                unsigned short* yrow = BX16 + (size_t)(row0 + r) * D;
#pragma unroll
                for (int j = 0; j < 4; ++j)
                    yrow[cg + 32 * j] = f2bf(acc[r][j]);
            }
        } else {
#pragma unroll
            for (int r = 0; r < 4; ++r) {
                float* yrow = AX + (size_t)(row0 + r) * D;
#pragma unroll
                for (int j = 0; j < 4; ++j) yrow[cg + 32 * j] = acc[r][j];
            }
        }
    }
}

// ---------------------------------------------------------------------------
// Histogram + per-edge rank: order[e] = indeg[dst[e]]++ (int atomics).
// First NCOPY_SM blocks stream an E_X stripe (co-resident overlap).
// ---------------------------------------------------------------------------
__global__ __launch_bounds__(256) void hist_kernel(
    const int* __restrict__ dst, int* __restrict__ indeg,
    int* __restrict__ order,
    const float4* __restrict__ exs, float4* __restrict__ exd, long cpb)
{
    if (blockIdx.x < NCOPY_SM) {
        if (cpb) copy_blk(exs, exd, HIST_C0 + (long)blockIdx.x * cpb, cpb);
        return;
    }
    const int b = blockIdx.x - NCOPY_SM;
    for (int e = b * 256 + threadIdx.x; e < NEDGES; e += MAIN_EDGE * 256)
        order[e] = atomicAdd(&indeg[dst[e]], 1);
}

// ---------------------------------------------------------------------------
// Scan: (1) per-block local exclusive scan + block totals, (2) scan totals.
// row_start[i] is computed on the fly later as bscan[i>>8] + lexc[i].
// ---------------------------------------------------------------------------
__global__ __launch_bounds__(256) void scan1_kernel(
    const int* __restrict__ indeg, int* __restrict__ lexc,
    int* __restrict__ bpart)
{
    __shared__ int ls[256];
    const int i = blockIdx.x * 256 + threadIdx.x;
    const int v = (i < NNODES) ? indeg[i] : 0;
    ls[threadIdx.x] = v;
    __syncthreads();
    for (int off = 1; off < 256; off <<= 1) {
        int u = (threadIdx.x >= off) ? ls[threadIdx.x - off] : 0;
        __syncthreads();
        ls[threadIdx.x] += u;
        __syncthreads();
    }
    if (i < NNODES) lexc[i] = ls[threadIdx.x] - v;
    if (threadIdx.x == 255) bpart[blockIdx.x] = ls[255];
}

__global__ __launch_bounds__(512) void scan2_kernel(
    const int* __restrict__ bpart, int* __restrict__ bscan)
{
    __shared__ int ls[512];
    const int t = threadIdx.x;
    const int v = (t < NBLK_P) ? bpart[t] : 0;
    ls[t] = v;
    __syncthreads();
    for (int off = 1; off < 512; off <<= 1) {
        int u = (t >= off) ? ls[t - off] : 0;
        __syncthreads();
        ls[t] += u;
        __syncthreads();
    }
    if (t < NBLK_P) bscan[t] = ls[t] - v;    // exclusive
}

// ---------------------------------------------------------------------------
// Fill CSR without atomics: esrc[bscan[v>>8] + lexc[v] + order[e]] = src[e].
// First NCOPY_SM blocks copy an E_X stripe.
// ---------------------------------------------------------------------------
__global__ __launch_bounds__(256) void fill_kernel(
    const int* __restrict__ src, const int* __restrict__ dst,
    const int* __restrict__ bscan, const int* __restrict__ lexc,
    const int* __restrict__ order, int* __restrict__ esrc,
    const float4* __restrict__ exs, float4* __restrict__ exd, long cpb)
{
    if (blockIdx.x < NCOPY_SM) {
        if (cpb) copy_blk(exs, exd, FILL_C0 + (long)blockIdx.x * cpb, cpb);
        return;
    }
    const int b = blockIdx.x - NCOPY_SM;
    for (int e = b * 256 + threadIdx.x; e < NEDGES; e += MAIN_EDGE * 256) {
        const int v = dst[e];
        esrc[bscan[v >> 8] + lexc[v] + order[e]] = src[e];
    }
}

// ---------------------------------------------------------------------------
// Gather-aggregate + fused Hpre: one wave per node, 64 lanes x 2 cols.
// BX is bf16 (one u32 per lane = 2 cols). First NCOPY_AGG blocks copy
// E_X stripes concurrently (agg is latency-bound with idle BW).
// ---------------------------------------------------------------------------
__global__ __launch_bounds__(256, 8) void agg_kernel(
    const float* __restrict__ AX, const unsigned* __restrict__ BX32,
    const float* __restrict__ X, const float* __restrict__ snorm,
    const int* __restrict__ bscan, const int* __restrict__ lexc,
    const int* __restrict__ indeg, const int* __restrict__ esrc,
    float* __restrict__ Hpre, float* __restrict__ psum,
    float* __restrict__ psq,
    const float4* __restrict__ exs, float4* __restrict__ exd, long cpb)
{
    if (blockIdx.x < NCOPY_AGG) {
        if (cpb) copy_blk(exs, exd, AGG_C0 + (long)blockIdx.x * cpb, cpb);
        return;
    }
    const int blk  = blockIdx.x - NCOPY_AGG;
    const int w    = threadIdx.x >> 6;   // wave in block, 0..3
    const int lane = threadIdx.x & 63;
    const int c0   = lane * 2;
    float ps0 = 0.f, ps1 = 0.f, q0 = 0.f, q1 = 0.f;

    for (int i = blk * 4 + w; i < NNODES; i += MAIN_AGG * 4) {
        const int rs  = bscan[i >> 8] + lexc[i];
        const int deg = indeg[i];
        const int re  = rs + deg;
        float ax, ay;
        if (deg > 0) {
            float2 a0 = *(const float2*)&AX[(size_t)i * D + c0];
            ax = a0.x; ay = a0.y;
            int e = rs;
            for (; e + 4 <= re; e += 4) {
                const int s0 = esrc[e + 0], s1 = esrc[e + 1];
                const int s2 = esrc[e + 2], s3 = esrc[e + 3];
                const unsigned v0 = BX32[s0 * 64 + lane];
                const unsigned v1 = BX32[s1 * 64 + lane];
                const unsigned v2 = BX32[s2 * 64 + lane];
                const unsigned v3 = BX32[s3 * 64 + lane];
                ax += bf_lo(v0) + bf_lo(v1) + bf_lo(v2) + bf_lo(v3);
                ay += bf_hi(v0) + bf_hi(v1) + bf_hi(v2) + bf_hi(v3);
            }
            for (; e < re; ++e) {
                const unsigned v = BX32[esrc[e] * 64 + lane];
                ax += bf_lo(v);
                ay += bf_hi(v);
            }
        } else {
            float2 x0 = *(const float2*)&X[(size_t)i * D + c0];
            ax = x0.x; ay = x0.y;
        }
        const float sn = snorm[i];
        ax *= sn; ay *= sn;
        *(float2*)&Hpre[(size_t)i * D + c0] = make_float2(ax, ay);
        ps0 += ax; ps1 += ay;
        q0  += ax * ax; q1 += ay * ay;
    }

    __shared__ float sp[4][D], sq[4][D];
    sp[w][c0] = ps0; sp[w][c0 + 1] = ps1;
    sq[w][c0] = q0;  sq[w][c0 + 1] = q1;
    __syncthreads();
    if (threadIdx.x < D) {
        const int c = threadIdx.x;
        psum[blk * D + c] = sp[0][c] + sp[1][c] + sp[2][c] + sp[3][c];
        psq [blk * D + c] = sq[0][c] + sq[1][c] + sq[2][c] + sq[3][c];
    }
}

// ---------------------------------------------------------------------------
// Reduce partials -> scale/shift for fused BN.
// ---------------------------------------------------------------------------
__global__ __launch_bounds__(1024) void bnstats_kernel(
    const float* __restrict__ psum, const float* __restrict__ psq,
    const float* __restrict__ gamma, const float* __restrict__ beta,
    float* __restrict__ scale, float* __restrict__ shift)
{
    const int c = threadIdx.x & 127;
    const int g = threadIdx.x >> 7;   // 0..7
    float s = 0.f, q = 0.f;
    for (int b = g; b < NB_STATS; b += 8) {
        s += psum[b * D + c];
        q += psq [b * D + c];
    }
    __shared__ float ls[8][D], lq[8][D];
    ls[g][c] = s;
    lq[g][c] = q;
    __syncthreads();
    if (threadIdx.x < D) {
        float S = 0.f, Q = 0.f;
#pragma unroll
        for (int g2 = 0; g2 < 8; ++g2) { S += ls[g2][c]; Q += lq[g2][c]; }
        const float inv_n = 1.0f / (float)NNODES;
        float mean = S * inv_n;
        float var  = Q * inv_n - mean * mean;
        float sc   = rsqrtf(var + BN_EPS) * gamma[c];
        scale[c] = sc;
        shift[c] = beta[c] - mean * sc;
    }
}

// ---------------------------------------------------------------------------
// out = X + relu(Hpre * scale + shift). First NCOPY_SM blocks copy E_X.
// ---------------------------------------------------------------------------
__global__ __launch_bounds__(256) void final_kernel(
    const float* __restrict__ Hpre, const float* __restrict__ X,
    const float* __restrict__ scale, const float* __restrict__ shift,
    float* __restrict__ out,
    const float4* __restrict__ exs, float4* __restrict__ exd, long cpb)
{
    if (blockIdx.x < NCOPY_SM) {
        if (cpb) copy_blk(exs, exd, FIN_C0 + (long)blockIdx.x * cpb, cpb);
        return;
    }
    const int b = blockIdx.x - NCOPY_SM;
    const int total = NNODES * D / 4;
    for (int i = b * 256 + threadIdx.x; i < total; i += MAIN_FIN * 256) {
        float4 h = ((const float4*)Hpre)[i];
        float4 x = ((const float4*)X)[i];
        int d0 = (i * 4) & 127;
        float4 r;
        r.x = x.x + fmaxf(0.f, h.x * scale[d0 + 0] + shift[d0 + 0]);
        r.y = x.y + fmaxf(0.f, h.y * scale[d0 + 1] + shift[d0 + 1]);
        r.z = x.z + fmaxf(0.f, h.z * scale[d0 + 2] + shift[d0 + 2]);
        r.w = x.w + fmaxf(0.f, h.w * scale[d0 + 3] + shift[d0 + 3]);
        ((float4*)out)[i] = r;
    }
}

extern "C" void kernel_launch(void* const* d_in, const int* in_sizes, int n_in,
                              void* d_out, int out_size, void* d_ws, size_t ws_size,
                              hipStream_t stream)
{
    const float* X       = (const float*)d_in[0];
    const float* E_X     = (const float*)d_in[1];
    const float* snorm_n = (const float*)d_in[2];
    const int*   src     = (const int*)d_in[4];
    const int*   dst     = (const int*)d_in[5];
    const float* A_w     = (const float*)d_in[6];
    const float* A_b     = (const float*)d_in[7];
    const float* B_w     = (const float*)d_in[8];
    const float* B_b     = (const float*)d_in[9];
    const float* gamma   = (const float*)d_in[10];
    const float* beta    = (const float*)d_in[11];

    float* out = (float*)d_out;
    const bool use_ws = (ws_size >= WS_NEED_BYTES);
    float* sb = use_ws ? (float*)d_ws : (out + (size_t)NNODES * D);

    float*          AX    = sb + OFF_AX;
    unsigned short* BX16  = (unsigned short*)(sb + OFF_BX16);
    int*            esrc  = (int*)(sb + OFF_ESRC);
    int*            order = (int*)(sb + OFF_ORDER);
    int*            indeg = (int*)(sb + OFF_INDEG);
    int*            lexc  = (int*)(sb + OFF_LEXC);
    int*            bpart = (int*)(sb + OFF_BPART);
    int*            bscan = (int*)(sb + OFF_BSCAN);
    float*          psum  = sb + OFF_PSUM;
    float*          psq   = sb + OFF_PSQ;
    float*          scale = sb + OFF_SCALE;
    float*          shift = sb + OFF_SHIFT;

    const float4* exs = (const float4*)E_X;
    float4*       exd = (float4*)(out + (size_t)NNODES * D);

    // Copy budgets: dedicated co-resident blocks when scratch is in d_ws,
    // else everything via the tail memcpy (scratch aliases exd region).
    const long cpb_sm   = use_ws ? CPB_SM : 0;
    const long cpb_agg  = use_ws ? CPB_AGG : 0;
    const long tail_from = use_ws ? TAIL_C0 : 0;

    hipMemsetAsync(indeg, 0, NNODES * sizeof(int), stream);

    gemm2_kernel<<<MAIN_GEMM, 256, 0, stream>>>(
        X, A_w, A_b, B_w, B_b, AX, BX16);
    hist_kernel<<<NCOPY_SM + MAIN_EDGE, 256, 0, stream>>>(
        dst, indeg, order, exs, exd, cpb_sm);
    scan1_kernel<<<NBLK_P, 256, 0, stream>>>(indeg, lexc, bpart);
    scan2_kernel<<<1, 512, 0, stream>>>(bpart, bscan);
    fill_kernel<<<NCOPY_SM + MAIN_EDGE, 256, 0, stream>>>(
        src, dst, bscan, lexc, order, esrc, exs, exd, cpb_sm);
    agg_kernel<<<NCOPY_AGG + MAIN_AGG, 256, 0, stream>>>(
        AX, (const unsigned*)BX16, X, snorm_n, bscan, lexc, indeg, esrc,
        out, psum, psq, exs, exd, cpb_agg);
    bnstats_kernel<<<1, 1024, 0, stream>>>(psum, psq, gamma, beta,
                                           scale, shift);
    final_kernel<<<NCOPY_SM + MAIN_FIN, 256, 0, stream>>>(
        out, X, scale, shift, out, exs, exd, cpb_sm);

    hipMemcpyAsync(exd + tail_from, exs + tail_from,
                   (size_t)(C_TOTAL - tail_from) * sizeof(float4),
                   hipMemcpyDeviceToDevice, stream);
}

// Round 7
// 752.721 us; speedup vs baseline: 1.0789x; 1.0789x over previous
//
#include <hip/hip_runtime.h>

#define D 128
#define NNODES 100000
#define NEDGES 1600000
#define BN_EPS 1e-5f
#define NB_STATS 2048
#define NBLK_P 391   // ceil(NNODES/256)

// Scratch layout, offsets in float slots RELATIVE to scratch base `sb`.
// sb = d_ws when ws_size is large enough, else the E_X region of d_out
// (tail copy overwrites scratch last; ordering identical either way).
#define OFF_AX     0          // 12.8M f32
#define OFF_BX16   12800000   // 12.8M bf16 = 6.4M slots
#define OFF_ESRC   19200000   // 1.6M int
#define OFF_ORDER  20800000   // 1.6M int
#define OFF_INDEG  22400000   // 100k int
#define OFF_LEXC   22620000   // 100k int
#define OFF_BPART  22730000   // 512 int
#define OFF_BSCAN  22731000   // 512 int
#define OFF_PSUM   22740000   // 2048*128 f32
#define OFF_PSQ    23010000   // 2048*128 f32
#define OFF_SCALE  23280000   // 128
#define OFF_SHIFT  23280128   // 128
#define WS_NEED_BYTES 93200000ull

#define MAIN_GEMM 512
#define MAIN_EDGE 2048
#define MAIN_AGG  2048
#define MAIN_FIN  2048

static __device__ __forceinline__ unsigned short f2bf(float f) {
    unsigned int u = __float_as_uint(f);
    u = (u + 0x7FFF + ((u >> 16) & 1)) >> 16;   // RNE, finite data
    return (unsigned short)u;
}
static __device__ __forceinline__ float bf_lo(unsigned v) {
    return __uint_as_float(v << 16);
}
static __device__ __forceinline__ float bf_hi(unsigned v) {
    return __uint_as_float(v & 0xFFFF0000u);
}

// ---------------------------------------------------------------------------
// GEMM: Y[i,d] = sum_k X[i,k] * W[d,k] + bias[d]
// Even blocks -> A (f32 AX), odd blocks -> B (bf16 BX16).
// ---------------------------------------------------------------------------
__global__ __launch_bounds__(256, 2) void gemm2_kernel(
    const float* __restrict__ X,
    const float* __restrict__ Aw, const float* __restrict__ Ab,
    const float* __restrict__ Bw, const float* __restrict__ Bb,
    float* __restrict__ AX, unsigned short* __restrict__ BX16)
{
    const bool isB = (blockIdx.x & 1);
    const float* __restrict__ W    = isB ? Bw : Aw;
    const float* __restrict__ bias = isB ? Bb : Ab;

    __shared__ float Ws[D * 132];
    const float4* W4 = (const float4*)W;
    for (int i = threadIdx.x; i < D * D / 4; i += 256) {
        int d  = i >> 5;
        int k4 = i & 31;
        float4 w = W4[i];
        *(float4*)&Ws[d * 132 + 4 * k4] = w;
    }
    __syncthreads();

    const int rg = threadIdx.x >> 5;   // 0..7  -> 4 rows each
    const int cg = threadIdx.x & 31;   // 0..31 -> cols cg+32j

    float b[4];
#pragma unroll
    for (int j = 0; j < 4; ++j) b[j] = bias[cg + 32 * j];

    const int ntiles = NNODES / 32;    // 3125 exact
    for (int t = (blockIdx.x >> 1); t < ntiles; t += (MAIN_GEMM >> 1)) {
        const int row0 = t * 32 + rg * 4;
        float acc[4][4];
#pragma unroll
        for (int r = 0; r < 4; ++r)
#pragma unroll
            for (int j = 0; j < 4; ++j) acc[r][j] = b[j];

        const float* xbase = X + (size_t)row0 * D;
#pragma unroll 4
        for (int k = 0; k < D; k += 4) {
            float4 xr[4];
#pragma unroll
            for (int r = 0; r < 4; ++r)
                xr[r] = *(const float4*)&xbase[r * D + k];
            float4 wv[4];
#pragma unroll
            for (int j = 0; j < 4; ++j)
                wv[j] = *(const float4*)&Ws[(cg + 32 * j) * 132 + k];
#pragma unroll
            for (int r = 0; r < 4; ++r)
#pragma unroll
                for (int j = 0; j < 4; ++j)
                    acc[r][j] += xr[r].x * wv[j].x + xr[r].y * wv[j].y +
                                 xr[r].z * wv[j].z + xr[r].w * wv[j].w;
        }
        if (isB) {
#pragma unroll
            for (int r = 0; r < 4; ++r) {
                unsigned short* yrow = BX16 + (size_t)(row0 + r) * D;
#pragma unroll
                for (int j = 0; j < 4; ++j)
                    yrow[cg + 32 * j] = f2bf(acc[r][j]);
            }
        } else {
#pragma unroll
            for (int r = 0; r < 4; ++r) {
                float* yrow = AX + (size_t)(row0 + r) * D;
#pragma unroll
                for (int j = 0; j < 4; ++j) yrow[cg + 32 * j] = acc[r][j];
            }
        }
    }
}

// ---------------------------------------------------------------------------
// Histogram + per-edge rank: order[e] = indeg[dst[e]]++ (int atomics).
// ---------------------------------------------------------------------------
__global__ __launch_bounds__(256) void hist_kernel(
    const int* __restrict__ dst, int* __restrict__ indeg,
    int* __restrict__ order)
{
    for (int e = blockIdx.x * 256 + threadIdx.x; e < NEDGES;
         e += MAIN_EDGE * 256)
        order[e] = atomicAdd(&indeg[dst[e]], 1);
}

// ---------------------------------------------------------------------------
// Scan: (1) per-block local exclusive scan + block totals, (2) scan totals.
// row_start[i] computed on the fly later as bscan[i>>8] + lexc[i].
// ---------------------------------------------------------------------------
__global__ __launch_bounds__(256) void scan1_kernel(
    const int* __restrict__ indeg, int* __restrict__ lexc,
    int* __restrict__ bpart)
{
    __shared__ int ls[256];
    const int i = blockIdx.x * 256 + threadIdx.x;
    const int v = (i < NNODES) ? indeg[i] : 0;
    ls[threadIdx.x] = v;
    __syncthreads();
    for (int off = 1; off < 256; off <<= 1) {
        int u = (threadIdx.x >= off) ? ls[threadIdx.x - off] : 0;
        __syncthreads();
        ls[threadIdx.x] += u;
        __syncthreads();
    }
    if (i < NNODES) lexc[i] = ls[threadIdx.x] - v;
    if (threadIdx.x == 255) bpart[blockIdx.x] = ls[255];
}

__global__ __launch_bounds__(512) void scan2_kernel(
    const int* __restrict__ bpart, int* __restrict__ bscan)
{
    __shared__ int ls[512];
    const int t = threadIdx.x;
    const int v = (t < NBLK_P) ? bpart[t] : 0;
    ls[t] = v;
    __syncthreads();
    for (int off = 1; off < 512; off <<= 1) {
        int u = (t >= off) ? ls[t - off] : 0;
        __syncthreads();
        ls[t] += u;
        __syncthreads();
    }
    if (t < NBLK_P) bscan[t] = ls[t] - v;    // exclusive
}

// ---------------------------------------------------------------------------
// Fill CSR without atomics: esrc[bscan[v>>8] + lexc[v] + order[e]] = src[e].
// ---------------------------------------------------------------------------
__global__ __launch_bounds__(256) void fill_kernel(
    const int* __restrict__ src, const int* __restrict__ dst,
    const int* __restrict__ bscan, const int* __restrict__ lexc,
    const int* __restrict__ order, int* __restrict__ esrc)
{
    for (int e = blockIdx.x * 256 + threadIdx.x; e < NEDGES;
         e += MAIN_EDGE * 256) {
        const int v = dst[e];
        esrc[bscan[v >> 8] + lexc[v] + order[e]] = src[e];
    }
}

// ---------------------------------------------------------------------------
// Gather-aggregate + fused Hpre, v2: HALF-WAVE per node.
// 32 lanes x uint2 (4 bf16 cols) per BX row; 2 nodes/wave; edge loop
// unrolled x4 -> 8 independent row-gathers in flight per wave.
// AX/X/Hpre are float4 per lane (16B). BN partials reduced via LDS.
// ---------------------------------------------------------------------------
__global__ __launch_bounds__(256, 8) void agg_kernel(
    const float4* __restrict__ AX4, const uint2* __restrict__ BX2,
    const float4* __restrict__ X4, const float* __restrict__ snorm,
    const int* __restrict__ bscan, const int* __restrict__ lexc,
    const int* __restrict__ indeg, const int* __restrict__ esrc,
    float4* __restrict__ Hpre4, float* __restrict__ psum,
    float* __restrict__ psq)
{
    const int w    = threadIdx.x >> 6;   // wave in block, 0..3
    const int lane = threadIdx.x & 63;
    const int half = lane >> 5;          // 0..1: node slot
    const int hl   = lane & 31;          // lane within half-wave
    float s0=0.f,s1=0.f,s2=0.f,s3=0.f, q0=0.f,q1=0.f,q2=0.f,q3=0.f;

    const int wid = blockIdx.x * 4 + w;  // 0..8191
    for (int base = wid * 2; base < NNODES; base += MAIN_AGG * 8) {
        const int i = base + half;
        if (i < NNODES) {
            float a0, a1, a2, a3;
            const int deg = indeg[i];
            if (deg > 0) {
                const int rs = bscan[i >> 8] + lexc[i];
                float4 a = AX4[(size_t)i * 32 + hl];
                a0 = a.x; a1 = a.y; a2 = a.z; a3 = a.w;
                int e = rs;
                const int re = rs + deg;
                for (; e + 4 <= re; e += 4) {
                    const uint2 v0 = BX2[(size_t)esrc[e + 0] * 32 + hl];
                    const uint2 v1 = BX2[(size_t)esrc[e + 1] * 32 + hl];
                    const uint2 v2 = BX2[(size_t)esrc[e + 2] * 32 + hl];
                    const uint2 v3 = BX2[(size_t)esrc[e + 3] * 32 + hl];
                    a0 += bf_lo(v0.x)+bf_lo(v1.x)+bf_lo(v2.x)+bf_lo(v3.x);
                    a1 += bf_hi(v0.x)+bf_hi(v1.x)+bf_hi(v2.x)+bf_hi(v3.x);
                    a2 += bf_lo(v0.y)+bf_lo(v1.y)+bf_lo(v2.y)+bf_lo(v3.y);
                    a3 += bf_hi(v0.y)+bf_hi(v1.y)+bf_hi(v2.y)+bf_hi(v3.y);
                }
                for (; e < re; ++e) {
                    const uint2 v = BX2[(size_t)esrc[e] * 32 + hl];
                    a0 += bf_lo(v.x); a1 += bf_hi(v.x);
                    a2 += bf_lo(v.y); a3 += bf_hi(v.y);
                }
            } else {
                float4 x = X4[(size_t)i * 32 + hl];
                a0 = x.x; a1 = x.y; a2 = x.z; a3 = x.w;
            }
            const float sn = snorm[i];
            a0 *= sn; a1 *= sn; a2 *= sn; a3 *= sn;
            Hpre4[(size_t)i * 32 + hl] = make_float4(a0, a1, a2, a3);
            s0 += a0; s1 += a1; s2 += a2; s3 += a3;
            q0 += a0*a0; q1 += a1*a1; q2 += a2*a2; q3 += a3*a3;
        }
    }

    __shared__ float sp[4][64][4], sq[4][64][4];
    sp[w][lane][0]=s0; sp[w][lane][1]=s1; sp[w][lane][2]=s2; sp[w][lane][3]=s3;
    sq[w][lane][0]=q0; sq[w][lane][1]=q1; sq[w][lane][2]=q2; sq[w][lane][3]=q3;
    __syncthreads();
    if (threadIdx.x < D) {
        const int c  = threadIdx.x;
        const int l0 = c >> 2;       // owning hl
        const int j  = c & 3;
        float S = 0.f, Q = 0.f;
#pragma unroll
        for (int w2 = 0; w2 < 4; ++w2) {
            S += sp[w2][l0][j] + sp[w2][32 + l0][j];
            Q += sq[w2][l0][j] + sq[w2][32 + l0][j];
        }
        psum[blockIdx.x * D + c] = S;
        psq [blockIdx.x * D + c] = Q;
    }
}

// ---------------------------------------------------------------------------
// Reduce partials -> scale/shift for fused BN.
// ---------------------------------------------------------------------------
__global__ __launch_bounds__(1024) void bnstats_kernel(
    const float* __restrict__ psum, const float* __restrict__ psq,
    const float* __restrict__ gamma, const float* __restrict__ beta,
    float* __restrict__ scale, float* __restrict__ shift)
{
    const int c = threadIdx.x & 127;
    const int g = threadIdx.x >> 7;   // 0..7
    float s = 0.f, q = 0.f;
    for (int b = g; b < NB_STATS; b += 8) {
        s += psum[b * D + c];
        q += psq [b * D + c];
    }
    __shared__ float ls[8][D], lq[8][D];
    ls[g][c] = s;
    lq[g][c] = q;
    __syncthreads();
    if (threadIdx.x < D) {
        float S = 0.f, Q = 0.f;
#pragma unroll
        for (int g2 = 0; g2 < 8; ++g2) { S += ls[g2][c]; Q += lq[g2][c]; }
        const float inv_n = 1.0f / (float)NNODES;
        float mean = S * inv_n;
        float var  = Q * inv_n - mean * mean;
        float sc   = rsqrtf(var + BN_EPS) * gamma[c];
        scale[c] = sc;
        shift[c] = beta[c] - mean * sc;
    }
}

// ---------------------------------------------------------------------------
// out = X + relu(Hpre * scale + shift).
// ---------------------------------------------------------------------------
__global__ __launch_bounds__(256) void final_kernel(
    const float* __restrict__ Hpre, const float* __restrict__ X,
    const float* __restrict__ scale, const float* __restrict__ shift,
    float* __restrict__ out)
{
    const int total = NNODES * D / 4;
    for (int i = blockIdx.x * 256 + threadIdx.x; i < total;
         i += MAIN_FIN * 256) {
        float4 h = ((const float4*)Hpre)[i];
        float4 x = ((const float4*)X)[i];
        int d0 = (i * 4) & 127;
        float4 r;
        r.x = x.x + fmaxf(0.f, h.x * scale[d0 + 0] + shift[d0 + 0]);
        r.y = x.y + fmaxf(0.f, h.y * scale[d0 + 1] + shift[d0 + 1]);
        r.z = x.z + fmaxf(0.f, h.z * scale[d0 + 2] + shift[d0 + 2]);
        r.w = x.w + fmaxf(0.f, h.w * scale[d0 + 3] + shift[d0 + 3]);
        ((float4*)out)[i] = r;
    }
}

extern "C" void kernel_launch(void* const* d_in, const int* in_sizes, int n_in,
                              void* d_out, int out_size, void* d_ws, size_t ws_size,
                              hipStream_t stream)
{
    const float* X       = (const float*)d_in[0];
    const float* E_X     = (const float*)d_in[1];
    const float* snorm_n = (const float*)d_in[2];
    const int*   src     = (const int*)d_in[4];
    const int*   dst     = (const int*)d_in[5];
    const float* A_w     = (const float*)d_in[6];
    const float* A_b     = (const float*)d_in[7];
    const float* B_w     = (const float*)d_in[8];
    const float* B_b     = (const float*)d_in[9];
    const float* gamma   = (const float*)d_in[10];
    const float* beta    = (const float*)d_in[11];

    float* out = (float*)d_out;
    const bool use_ws = (ws_size >= WS_NEED_BYTES);
    float* sb = use_ws ? (float*)d_ws : (out + (size_t)NNODES * D);

    float*          AX    = sb + OFF_AX;
    unsigned short* BX16  = (unsigned short*)(sb + OFF_BX16);
    int*            esrc  = (int*)(sb + OFF_ESRC);
    int*            order = (int*)(sb + OFF_ORDER);
    int*            indeg = (int*)(sb + OFF_INDEG);
    int*            lexc  = (int*)(sb + OFF_LEXC);
    int*            bpart = (int*)(sb + OFF_BPART);
    int*            bscan = (int*)(sb + OFF_BSCAN);
    float*          psum  = sb + OFF_PSUM;
    float*          psq   = sb + OFF_PSQ;
    float*          scale = sb + OFF_SCALE;
    float*          shift = sb + OFF_SHIFT;

    hipMemsetAsync(indeg, 0, NNODES * sizeof(int), stream);

    gemm2_kernel<<<MAIN_GEMM, 256, 0, stream>>>(
        X, A_w, A_b, B_w, B_b, AX, BX16);
    hist_kernel<<<MAIN_EDGE, 256, 0, stream>>>(dst, indeg, order);
    scan1_kernel<<<NBLK_P, 256, 0, stream>>>(indeg, lexc, bpart);
    scan2_kernel<<<1, 512, 0, stream>>>(bpart, bscan);
    fill_kernel<<<MAIN_EDGE, 256, 0, stream>>>(
        src, dst, bscan, lexc, order, esrc);
    agg_kernel<<<MAIN_AGG, 256, 0, stream>>>(
        (const float4*)AX, (const uint2*)BX16, (const float4*)X, snorm_n,
        bscan, lexc, indeg, esrc, (float4*)out, psum, psq);
    bnstats_kernel<<<1, 1024, 0, stream>>>(psum, psq, gamma, beta,
                                           scale, shift);
    final_kernel<<<MAIN_FIN, 256, 0, stream>>>(out, X, scale, shift, out);

    // E_X passthrough tail.
    hipMemcpyAsync(out + (size_t)NNODES * D, E_X,
                   (size_t)NEDGES * D * sizeof(float),
                   hipMemcpyDeviceToDevice, stream);
}

// Round 8
// 659.430 us; speedup vs baseline: 1.2315x; 1.1415x over previous
//
#include <hip/hip_runtime.h>

#define D 128
#define NNODES 100000
#define NEDGES 1600000
#define BN_EPS 1e-5f
#define NB_STATS 2048
#define NBLK_P 391   // ceil(NNODES/256)
#define NTILES 1563  // ceil(NNODES/64)

// Scratch layout, offsets in float slots RELATIVE to scratch base `sb`.
// sb = d_ws when ws_size is large enough, else the E_X region of d_out
// (tail copy overwrites scratch last; ordering identical either way).
#define OFF_AX     0          // 12.8M f32
#define OFF_BX16   12800000   // 12.8M bf16 = 6.4M slots
#define OFF_ESRC   19200000   // 1.6M int
#define OFF_ORDER  20800000   // 1.6M int
#define OFF_INDEG  22400000   // 100k int
#define OFF_LEXC   22620000   // 100k int
#define OFF_BPART  22730000   // 512 int
#define OFF_BSCAN  22731000   // 512 int
#define OFF_PSUM   22740000   // 2048*128 f32
#define OFF_PSQ    23010000   // 2048*128 f32
#define OFF_SCALE  23280000   // 128
#define OFF_SHIFT  23280128   // 128
#define WS_NEED_BYTES 93200000ull

#define MAIN_GEMM 512
#define MAIN_EDGE 2048
#define MAIN_AGG  2048
#define MAIN_FIN  2048

typedef __attribute__((ext_vector_type(8))) short bf16x8;
typedef __attribute__((ext_vector_type(4))) float f32x4;

static __device__ __forceinline__ unsigned short f2bf(float f) {
    unsigned int u = __float_as_uint(f);
    u = (u + 0x7FFF + ((u >> 16) & 1)) >> 16;   // RNE, finite data
    return (unsigned short)u;
}
static __device__ __forceinline__ float bf_lo(unsigned v) {
    return __uint_as_float(v << 16);
}
static __device__ __forceinline__ float bf_hi(unsigned v) {
    return __uint_as_float(v & 0xFFFF0000u);
}
static __device__ __forceinline__ bf16x8 pack8(float4 a, float4 b) {
    union { uint4 u; bf16x8 v; } r;
    r.u.x = (unsigned)f2bf(a.x) | ((unsigned)f2bf(a.y) << 16);
    r.u.y = (unsigned)f2bf(a.z) | ((unsigned)f2bf(a.w) << 16);
    r.u.z = (unsigned)f2bf(b.x) | ((unsigned)f2bf(b.y) << 16);
    r.u.w = (unsigned)f2bf(b.z) | ((unsigned)f2bf(b.w) << 16);
    return r.v;
}

// ---------------------------------------------------------------------------
// MFMA GEMM: Y[i,d] = sum_k X[i,k] * W[d,k] + bias[d], both A and B.
// 64-row tile per block iter; 4 waves: wave = (matrix<<1)|colhalf.
// X tile staged as bf16 in LDS (shared); W frags held in registers.
// mfma_f32_16x16x32_bf16: a lane l: row=l&15, k=ks*32+(l>>4)*8+j (X row)
//                         b lane l: col=l&15, k likewise (W row)
//                         C lane l reg r: row=(l>>4)*4+r, col=l&15 (m89)
// ---------------------------------------------------------------------------
__global__ __launch_bounds__(256, 2) void gemm2_kernel(
    const float* __restrict__ X,
    const float* __restrict__ Aw, const float* __restrict__ Ab,
    const float* __restrict__ Bw, const float* __restrict__ Bb,
    float* __restrict__ AX, unsigned short* __restrict__ BX16)
{
    __shared__ unsigned short Xs[64][136];   // 272B row stride, 2-way free

    const int w    = threadIdx.x >> 6;   // wave 0..3
    const int lane = threadIdx.x & 63;
    const bool isB = (w >> 1);
    const int colbase = (w & 1) * 64;
    const int bn   = lane & 15;          // col-in-tile / row-in-tile
    const int kg   = lane >> 4;          // k-group 0..3 (8 k each)

    const float* __restrict__ Wm   = isB ? Bw : Aw;
    const float* __restrict__ bias = isB ? Bb : Ab;

    // W fragments in registers: wf[ks][ct], ct = coltile within 64 cols.
    bf16x8 wf[4][4];
#pragma unroll
    for (int ks = 0; ks < 4; ++ks)
#pragma unroll
        for (int ct = 0; ct < 4; ++ct) {
            const int d = colbase + ct * 16 + bn;
            const int k = ks * 32 + kg * 8;
            const float4* wp = (const float4*)&Wm[d * D + k];
            wf[ks][ct] = pack8(wp[0], wp[1]);
        }

    float bias4[4];
#pragma unroll
    for (int ct = 0; ct < 4; ++ct) bias4[ct] = bias[colbase + ct * 16 + bn];

    for (int t = blockIdx.x; t < NTILES; t += MAIN_GEMM) {
        const int row0 = t * 64;
        // stage X tile (f32 -> bf16 LDS), 8 elems per chunk
        for (int c = threadIdx.x; c < 1024; c += 256) {
            const int r   = c >> 4;
            const int col = (c & 15) * 8;
            const int row = min(row0 + r, NNODES - 1);
            const float4* xp = (const float4*)&X[(size_t)row * D + col];
            const float4 x0 = xp[0], x1 = xp[1];
            union { uint4 u; } pk;
            pk.u.x = (unsigned)f2bf(x0.x) | ((unsigned)f2bf(x0.y) << 16);
            pk.u.y = (unsigned)f2bf(x0.z) | ((unsigned)f2bf(x0.w) << 16);
            pk.u.z = (unsigned)f2bf(x1.x) | ((unsigned)f2bf(x1.y) << 16);
            pk.u.w = (unsigned)f2bf(x1.z) | ((unsigned)f2bf(x1.w) << 16);
            *(uint4*)&Xs[r][col] = pk.u;
        }
        __syncthreads();

        f32x4 acc[4][4];   // [rowtile][coltile]
#pragma unroll
        for (int rt = 0; rt < 4; ++rt)
#pragma unroll
            for (int ct = 0; ct < 4; ++ct)
                acc[rt][ct] = (f32x4){0.f, 0.f, 0.f, 0.f};

#pragma unroll
        for (int ks = 0; ks < 4; ++ks) {
            bf16x8 a[4];
#pragma unroll
            for (int rt = 0; rt < 4; ++rt)
                a[rt] = *(const bf16x8*)&Xs[rt * 16 + bn][ks * 32 + kg * 8];
#pragma unroll
            for (int rt = 0; rt < 4; ++rt)
#pragma unroll
                for (int ct = 0; ct < 4; ++ct)
                    acc[rt][ct] = __builtin_amdgcn_mfma_f32_16x16x32_bf16(
                        a[rt], wf[ks][ct], acc[rt][ct], 0, 0, 0);
        }
        __syncthreads();

        // epilogue: C row=(lane>>4)*4+r, col=lane&15 within each 16x16
#pragma unroll
        for (int rt = 0; rt < 4; ++rt) {
#pragma unroll
            for (int r = 0; r < 4; ++r) {
                const int row = row0 + rt * 16 + kg * 4 + r;
                if (row < NNODES) {
                    if (!isB) {
                        float* yrow = AX + (size_t)row * D + colbase;
#pragma unroll
                        for (int ct = 0; ct < 4; ++ct)
                            yrow[ct * 16 + bn] = acc[rt][ct][r] + bias4[ct];
                    } else {
                        unsigned short* yrow = BX16 + (size_t)row * D + colbase;
#pragma unroll
                        for (int ct = 0; ct < 4; ++ct)
                            yrow[ct * 16 + bn] =
                                f2bf(acc[rt][ct][r] + bias4[ct]);
                    }
                }
            }
        }
    }
}

// ---------------------------------------------------------------------------
// Histogram + per-edge rank: order[e] = indeg[dst[e]]++ (int atomics).
// ---------------------------------------------------------------------------
__global__ __launch_bounds__(256) void hist_kernel(
    const int* __restrict__ dst, int* __restrict__ indeg,
    int* __restrict__ order)
{
    for (int e = blockIdx.x * 256 + threadIdx.x; e < NEDGES;
         e += MAIN_EDGE * 256)
        order[e] = atomicAdd(&indeg[dst[e]], 1);
}

// ---------------------------------------------------------------------------
// Scan: (1) per-block local exclusive scan + block totals, (2) scan totals.
// row_start[i] computed on the fly later as bscan[i>>8] + lexc[i].
// ---------------------------------------------------------------------------
__global__ __launch_bounds__(256) void scan1_kernel(
    const int* __restrict__ indeg, int* __restrict__ lexc,
    int* __restrict__ bpart)
{
    __shared__ int ls[256];
    const int i = blockIdx.x * 256 + threadIdx.x;
    const int v = (i < NNODES) ? indeg[i] : 0;
    ls[threadIdx.x] = v;
    __syncthreads();
    for (int off = 1; off < 256; off <<= 1) {
        int u = (threadIdx.x >= off) ? ls[threadIdx.x - off] : 0;
        __syncthreads();
        ls[threadIdx.x] += u;
        __syncthreads();
    }
    if (i < NNODES) lexc[i] = ls[threadIdx.x] - v;
    if (threadIdx.x == 255) bpart[blockIdx.x] = ls[255];
}

__global__ __launch_bounds__(512) void scan2_kernel(
    const int* __restrict__ bpart, int* __restrict__ bscan)
{
    __shared__ int ls[512];
    const int t = threadIdx.x;
    const int v = (t < NBLK_P) ? bpart[t] : 0;
    ls[t] = v;
    __syncthreads();
    for (int off = 1; off < 512; off <<= 1) {
        int u = (t >= off) ? ls[t - off] : 0;
        __syncthreads();
        ls[t] += u;
        __syncthreads();
    }
    if (t < NBLK_P) bscan[t] = ls[t] - v;    // exclusive
}

// ---------------------------------------------------------------------------
// Fill CSR without atomics: esrc[bscan[v>>8] + lexc[v] + order[e]] = src[e].
// ---------------------------------------------------------------------------
__global__ __launch_bounds__(256) void fill_kernel(
    const int* __restrict__ src, const int* __restrict__ dst,
    const int* __restrict__ bscan, const int* __restrict__ lexc,
    const int* __restrict__ order, int* __restrict__ esrc)
{
    for (int e = blockIdx.x * 256 + threadIdx.x; e < NEDGES;
         e += MAIN_EDGE * 256) {
        const int v = dst[e];
        esrc[bscan[v >> 8] + lexc[v] + order[e]] = src[e];
    }
}

// ---------------------------------------------------------------------------
// Gather-aggregate + fused Hpre: HALF-WAVE per node.
// 32 lanes x uint2 (4 bf16 cols) per BX row; 2 nodes/wave; edge loop
// unrolled x4 -> 8 independent row-gathers in flight per wave.
// ---------------------------------------------------------------------------
__global__ __launch_bounds__(256, 8) void agg_kernel(
    const float4* __restrict__ AX4, const uint2* __restrict__ BX2,
    const float4* __restrict__ X4, const float* __restrict__ snorm,
    const int* __restrict__ bscan, const int* __restrict__ lexc,
    const int* __restrict__ indeg, const int* __restrict__ esrc,
    float4* __restrict__ Hpre4, float* __restrict__ psum,
    float* __restrict__ psq)
{
    const int w    = threadIdx.x >> 6;   // wave in block, 0..3
    const int lane = threadIdx.x & 63;
    const int half = lane >> 5;          // 0..1: node slot
    const int hl   = lane & 31;          // lane within half-wave
    float s0=0.f,s1=0.f,s2=0.f,s3=0.f, q0=0.f,q1=0.f,q2=0.f,q3=0.f;

    const int wid = blockIdx.x * 4 + w;  // 0..8191
    for (int base = wid * 2; base < NNODES; base += MAIN_AGG * 8) {
        const int i = base + half;
        if (i < NNODES) {
            float a0, a1, a2, a3;
            const int deg = indeg[i];
            if (deg > 0) {
                const int rs = bscan[i >> 8] + lexc[i];
                float4 a = AX4[(size_t)i * 32 + hl];
                a0 = a.x; a1 = a.y; a2 = a.z; a3 = a.w;
                int e = rs;
                const int re = rs + deg;
                for (; e + 4 <= re; e += 4) {
                    const uint2 v0 = BX2[(size_t)esrc[e + 0] * 32 + hl];
                    const uint2 v1 = BX2[(size_t)esrc[e + 1] * 32 + hl];
                    const uint2 v2 = BX2[(size_t)esrc[e + 2] * 32 + hl];
                    const uint2 v3 = BX2[(size_t)esrc[e + 3] * 32 + hl];
                    a0 += bf_lo(v0.x)+bf_lo(v1.x)+bf_lo(v2.x)+bf_lo(v3.x);
                    a1 += bf_hi(v0.x)+bf_hi(v1.x)+bf_hi(v2.x)+bf_hi(v3.x);
                    a2 += bf_lo(v0.y)+bf_lo(v1.y)+bf_lo(v2.y)+bf_lo(v3.y);
                    a3 += bf_hi(v0.y)+bf_hi(v1.y)+bf_hi(v2.y)+bf_hi(v3.y);
                }
                for (; e < re; ++e) {
                    const uint2 v = BX2[(size_t)esrc[e] * 32 + hl];
                    a0 += bf_lo(v.x); a1 += bf_hi(v.x);
                    a2 += bf_lo(v.y); a3 += bf_hi(v.y);
                }
            } else {
                float4 x = X4[(size_t)i * 32 + hl];
                a0 = x.x; a1 = x.y; a2 = x.z; a3 = x.w;
            }
            const float sn = snorm[i];
            a0 *= sn; a1 *= sn; a2 *= sn; a3 *= sn;
            Hpre4[(size_t)i * 32 + hl] = make_float4(a0, a1, a2, a3);
            s0 += a0; s1 += a1; s2 += a2; s3 += a3;
            q0 += a0*a0; q1 += a1*a1; q2 += a2*a2; q3 += a3*a3;
        }
    }

    __shared__ float sp[4][64][4], sq[4][64][4];
    sp[w][lane][0]=s0; sp[w][lane][1]=s1; sp[w][lane][2]=s2; sp[w][lane][3]=s3;
    sq[w][lane][0]=q0; sq[w][lane][1]=q1; sq[w][lane][2]=q2; sq[w][lane][3]=q3;
    __syncthreads();
    if (threadIdx.x < D) {
        const int c  = threadIdx.x;
        const int l0 = c >> 2;       // owning hl
        const int j  = c & 3;
        float S = 0.f, Q = 0.f;
#pragma unroll
        for (int w2 = 0; w2 < 4; ++w2) {
            S += sp[w2][l0][j] + sp[w2][32 + l0][j];
            Q += sq[w2][l0][j] + sq[w2][32 + l0][j];
        }
        psum[blockIdx.x * D + c] = S;
        psq [blockIdx.x * D + c] = Q;
    }
}

// ---------------------------------------------------------------------------
// Reduce partials -> scale/shift for fused BN.
// ---------------------------------------------------------------------------
__global__ __launch_bounds__(1024) void bnstats_kernel(
    const float* __restrict__ psum, const float* __restrict__ psq,
    const float* __restrict__ gamma, const float* __restrict__ beta,
    float* __restrict__ scale, float* __restrict__ shift)
{
    const int c = threadIdx.x & 127;
    const int g = threadIdx.x >> 7;   // 0..7
    float s = 0.f, q = 0.f;
    for (int b = g; b < NB_STATS; b += 8) {
        s += psum[b * D + c];
        q += psq [b * D + c];
    }
    __shared__ float ls[8][D], lq[8][D];
    ls[g][c] = s;
    lq[g][c] = q;
    __syncthreads();
    if (threadIdx.x < D) {
        float S = 0.f, Q = 0.f;
#pragma unroll
        for (int g2 = 0; g2 < 8; ++g2) { S += ls[g2][c]; Q += lq[g2][c]; }
        const float inv_n = 1.0f / (float)NNODES;
        float mean = S * inv_n;
        float var  = Q * inv_n - mean * mean;
        float sc   = rsqrtf(var + BN_EPS) * gamma[c];
        scale[c] = sc;
        shift[c] = beta[c] - mean * sc;
    }
}

// ---------------------------------------------------------------------------
// out = X + relu(Hpre * scale + shift).
// ---------------------------------------------------------------------------
__global__ __launch_bounds__(256) void final_kernel(
    const float* __restrict__ Hpre, const float* __restrict__ X,
    const float* __restrict__ scale, const float* __restrict__ shift,
    float* __restrict__ out)
{
    const int total = NNODES * D / 4;
    for (int i = blockIdx.x * 256 + threadIdx.x; i < total;
         i += MAIN_FIN * 256) {
        float4 h = ((const float4*)Hpre)[i];
        float4 x = ((const float4*)X)[i];
        int d0 = (i * 4) & 127;
        float4 r;
        r.x = x.x + fmaxf(0.f, h.x * scale[d0 + 0] + shift[d0 + 0]);
        r.y = x.y + fmaxf(0.f, h.y * scale[d0 + 1] + shift[d0 + 1]);
        r.z = x.z + fmaxf(0.f, h.z * scale[d0 + 2] + shift[d0 + 2]);
        r.w = x.w + fmaxf(0.f, h.w * scale[d0 + 3] + shift[d0 + 3]);
        ((float4*)out)[i] = r;
    }
}

extern "C" void kernel_launch(void* const* d_in, const int* in_sizes, int n_in,
                              void* d_out, int out_size, void* d_ws, size_t ws_size,
                              hipStream_t stream)
{
    const float* X       = (const float*)d_in[0];
    const float* E_X     = (const float*)d_in[1];
    const float* snorm_n = (const float*)d_in[2];
    const int*   src     = (const int*)d_in[4];
    const int*   dst     = (const int*)d_in[5];
    const float* A_w     = (const float*)d_in[6];
    const float* A_b     = (const float*)d_in[7];
    const float* B_w     = (const float*)d_in[8];
    const float* B_b     = (const float*)d_in[9];
    const float* gamma   = (const float*)d_in[10];
    const float* beta    = (const float*)d_in[11];

    float* out = (float*)d_out;
    const bool use_ws = (ws_size >= WS_NEED_BYTES);
    float* sb = use_ws ? (float*)d_ws : (out + (size_t)NNODES * D);

    float*          AX    = sb + OFF_AX;
    unsigned short* BX16  = (unsigned short*)(sb + OFF_BX16);
    int*            esrc  = (int*)(sb + OFF_ESRC);
    int*            order = (int*)(sb + OFF_ORDER);
    int*            indeg = (int*)(sb + OFF_INDEG);
    int*            lexc  = (int*)(sb + OFF_LEXC);
    int*            bpart = (int*)(sb + OFF_BPART);
    int*            bscan = (int*)(sb + OFF_BSCAN);
    float*          psum  = sb + OFF_PSUM;
    float*          psq   = sb + OFF_PSQ;
    float*          scale = sb + OFF_SCALE;
    float*          shift = sb + OFF_SHIFT;

    hipMemsetAsync(indeg, 0, NNODES * sizeof(int), stream);

    gemm2_kernel<<<MAIN_GEMM, 256, 0, stream>>>(
        X, A_w, A_b, B_w, B_b, AX, BX16);
    hist_kernel<<<MAIN_EDGE, 256, 0, stream>>>(dst, indeg, order);
    scan1_kernel<<<NBLK_P, 256, 0, stream>>>(indeg, lexc, bpart);
    scan2_kernel<<<1, 512, 0, stream>>>(bpart, bscan);
    fill_kernel<<<MAIN_EDGE, 256, 0, stream>>>(
        src, dst, bscan, lexc, order, esrc);
    agg_kernel<<<MAIN_AGG, 256, 0, stream>>>(
        (const float4*)AX, (const uint2*)BX16, (const float4*)X, snorm_n,
        bscan, lexc, indeg, esrc, (float4*)out, psum, psq);
    bnstats_kernel<<<1, 1024, 0, stream>>>(psum, psq, gamma, beta,
                                           scale, shift);
    final_kernel<<<MAIN_FIN, 256, 0, stream>>>(out, X, scale, shift, out);

    // E_X passthrough tail.
    hipMemcpyAsync(out + (size_t)NNODES * D, E_X,
                   (size_t)NEDGES * D * sizeof(float),
                   hipMemcpyDeviceToDevice, stream);
}